// Round 20
// baseline (34.960 us; speedup 1.0000x reference)
//
#include <hip/hip_runtime.h>
#include <math.h>

// OrthogonalButterfly: X (1024 x 8192) fp32, 20 butterfly layers, stride 2^(l%10).
// R18/R19 = 29.8/29.5us (MFMA path). R19 lesson: grid 256 = #CUs, so the 2
// blocks/CU capacity was never used -> still 1 serial chain per CU.
// R20: 16-col blocks (256 thr, 4 waves), site = rb, 32KB LDS, grid 512 ->
// genuinely 2 resident blocks/CU; each wave handles 8 rb-classes (rb=w+4m).
// Fragment packing, boundary algebra, numerics byte-identical (absmax 0.031).
// Fallback: R15 tab/notab paths if ws_size < 512KB.

#define NROW   1024
#define BATCH  8192
#define BATCH2 (BATCH / 2)
#define DEPTH  20
#define NANG   512
#define TAB_ELEMS (DEPTH * NANG)
#define TAB_BYTES ((size_t)TAB_ELEMS * 8)
#define WS_MFMA_BYTES ((size_t)(4 * 32 * 1024) * 2 * 2)   // hi+lo, 512KB

typedef float v2f __attribute__((ext_vector_type(2)));
using bf16x8 = __attribute__((ext_vector_type(8))) short;
using f32x4  = __attribute__((ext_vector_type(4))) float;

__device__ __forceinline__ unsigned short f2b(float f) {
    union { float f; unsigned int u; } v; v.f = f;
    unsigned int u = v.u;
    return (unsigned short)((u + 0x7FFFu + ((u >> 16) & 1u)) >> 16);
}
__device__ __forceinline__ float b2f(unsigned short b) {
    union { unsigned int u; float f; } v; v.u = ((unsigned int)b) << 16;
    return v.f;
}

// ================= MFMA path =================
// W[grp][b] 32x32 row-major: column j = 5 butterfly layers applied to e_j.
// Builder (R18-proven): wave widx handles matrices (grp, bpair*2+{0,1}).
__global__ __launch_bounds__(64) void build_w_kernel(
        const float* __restrict__ ang,
        unsigned short* __restrict__ whi,
        unsigned short* __restrict__ wlo) {
    __shared__ float2 cs[160];           // [h*80 + q*16 + p]
    int ln = threadIdx.x;                // [0,64)
    int widx = blockIdx.x;               // [0,64)
    int grp = widx >> 4;                 // [0,4)
    int bpair = widx & 15;               // [0,16)

    // phase 1: cooperative sincos of the 160 shared angles
    #pragma unroll
    for (int rnd = 0; rnd < 3; ++rnd) {
        int tt = ln + rnd * 64;
        if (tt < 160) {
            int h = tt >= 80;
            int u = tt - h * 80;
            int q = u >> 4, p = u & 15;
            int b = bpair * 2 + h;
            int sp = (grp & 1) ? q + 5 : q;
            int l  = grp * 5 + q;
            int s  = 1 << sp;
            int SL = 1 << q;
            int i0 = ((p >> q) << (q + 1)) | (p & (SL - 1));
            int r0 = (grp & 1) ? ((i0 << 5) | b) : ((b << 5) | i0);
            int a  = ((r0 >> (sp + 1)) << sp) | (r0 & (s - 1));
            float th = ang[l * NANG + a];
            float sv, cv;
            __sincosf(th, &sv, &cv);
            cs[tt] = make_float2(cv, sv);
        }
    }
    __syncthreads();

    // phase 2: lane (h, j) builds column j of matrix (grp, bpair*2+h)
    int h = ln >> 5, j = ln & 31;
    int b = bpair * 2 + h;
    float v[32];
    #pragma unroll
    for (int i = 0; i < 32; ++i) v[i] = (i == j) ? 1.f : 0.f;
    #pragma unroll
    for (int q = 0; q < 5; ++q) {
        int SL = 1 << q;
        #pragma unroll
        for (int p = 0; p < 16; ++p) {
            int i0 = ((p >> q) << (q + 1)) | (p & (SL - 1));
            int i1 = i0 + SL;
            float2 q2 = cs[h * 80 + q * 16 + p];   // broadcast read
            float x0 = v[i0], x1 = v[i1];
            v[i0] = q2.x * x0 + q2.y * x1;
            v[i1] = q2.x * x1 - q2.y * x0;
        }
    }
    int mat = grp * 32 + b;
    #pragma unroll
    for (int i = 0; i < 32; ++i) {
        unsigned short hh = f2b(v[i]);
        whi[mat * 1024 + i * 32 + j] = hh;               // coalesced 64B/half
        wlo[mat * 1024 + i * 32 + j] = f2b(v[i] - b2f(hh));
    }
}

// Tile layout (bf16): ushort idx = site*512 + (k>>3)*128 + cc*8 + (k&7)
//   site = rb (32 sites x 1KB = 32KB)
__global__ __launch_bounds__(256, 4) void mfma_kernel(
        const float* __restrict__ X,
        const unsigned short* __restrict__ whi,
        const unsigned short* __restrict__ wlo,
        float* __restrict__ out) {
    __shared__ __align__(16) unsigned short sbuf[16384];   // 32KB
    int t  = threadIdx.x;
    int ln = t & 63;
    int w  = t >> 6;                          // wave id [0,4)
    int bid = blockIdx.x;
    int L = ((bid & 7) << 6) | (bid >> 3);    // XCD swizzle, bijective (512=8*64)
    int col0 = L << 4;                        // 16 cols per block

    // ---- entry: fp32 global -> bf16 tiles ----
    {
        int cc = t & 15, bb = t >> 4;         // bb in [0,16)
        int col = col0 + cc;
        #pragma unroll
        for (int half = 0; half < 2; ++half) {
            int rb = bb + 16 * half;
            #pragma unroll
            for (int g = 0; g < 4; ++g) {
                unsigned int uu[4];
                #pragma unroll
                for (int jj = 0; jj < 4; ++jj) {
                    float va = X[(rb * 32 + g * 8 + 2 * jj) * BATCH + col];
                    float vb = X[(rb * 32 + g * 8 + 2 * jj + 1) * BATCH + col];
                    uu[jj] = (unsigned int)f2b(va) | ((unsigned int)f2b(vb) << 16);
                }
                *reinterpret_cast<uint4*>(&sbuf[rb * 512 + g * 128 + cc * 8]) =
                    make_uint4(uu[0], uu[1], uu[2], uu[3]);
            }
        }
    }
    __syncthreads();

    const bf16x8* WH = reinterpret_cast<const bf16x8*>(whi);
    const bf16x8* WL = reinterpret_cast<const bf16x8*>(wlo);
    int r15 = ln & 15, kg = ln >> 4;

    #pragma unroll
    for (int grp = 0; grp < 4; ++grp) {
        // ---- batched reads: all 8 B-fragments for this group ----
        bf16x8 bf[8];
        #pragma unroll
        for (int m = 0; m < 8; ++m) {
            int rb = w + 4 * m;
            bf[m] = *reinterpret_cast<const bf16x8*>(
                &sbuf[rb * 512 + kg * 128 + r15 * 8]);
        }
        if (grp < 3) __syncthreads();    // all reads done before any write

        #pragma unroll
        for (int m = 0; m < 8; ++m) {
            int rb  = w + 4 * m;
            int mat = grp * 32 + rb;
            // A-frags: lane holds W[row=r15(+16)][k=kg*8..+7] (16B contiguous)
            bf16x8 ah0 = WH[mat * 128 + (r15     ) * 4 + kg];
            bf16x8 ah1 = WH[mat * 128 + (r15 + 16) * 4 + kg];
            bf16x8 al0 = WL[mat * 128 + (r15     ) * 4 + kg];
            bf16x8 al1 = WL[mat * 128 + (r15 + 16) * 4 + kg];
            bf16x8 b = bf[m];
            f32x4 acc0 = {0.f, 0.f, 0.f, 0.f};
            f32x4 acc1 = {0.f, 0.f, 0.f, 0.f};
            acc0 = __builtin_amdgcn_mfma_f32_16x16x32_bf16(ah0, b, acc0, 0, 0, 0);
            acc0 = __builtin_amdgcn_mfma_f32_16x16x32_bf16(al0, b, acc0, 0, 0, 0);
            acc1 = __builtin_amdgcn_mfma_f32_16x16x32_bf16(ah1, b, acc1, 0, 0, 0);
            acc1 = __builtin_amdgcn_mfma_f32_16x16x32_bf16(al1, b, acc1, 0, 0, 0);
            if (grp < 3) {
                // boundary: new site' = old_row k, new k' = rb
                #pragma unroll
                for (int e = 0; e < 4; ++e) {
                    int k0 = kg * 4 + e;
                    int k1 = 16 + kg * 4 + e;
                    sbuf[k0 * 512 + (rb >> 3) * 128 + r15 * 8 + (rb & 7)] =
                        f2b(acc0[e]);
                    sbuf[k1 * 512 + (rb >> 3) * 128 + r15 * 8 + (rb & 7)] =
                        f2b(acc1[e]);
                }
            } else {
                // G3 is B-space: r = k*32 + rb; direct coalesced store
                int col = col0 + r15;
                #pragma unroll
                for (int e = 0; e < 4; ++e) {
                    int r0 = (kg * 4 + e) * 32 + rb;
                    int r1 = (16 + kg * 4 + e) * 32 + rb;
                    out[r0 * BATCH + col] = acc0[e];
                    out[r1 * BATCH + col] = acc1[e];
                }
            }
        }
        if (grp < 3) __syncthreads();    // writes done before next group's reads
    }
}

// ================= fallback: R15 path (proven 31.6us) =================
__device__ __host__ __forceinline__ int rowA(int sub, int i){ return (sub << 5) | i; }
__device__ __host__ __forceinline__ int rowB(int sub, int i){ return sub | (i << 5); }

__global__ void build_tab_kernel(const float* __restrict__ ang,
                                 float2* __restrict__ tab) {
    int idx = blockIdx.x * blockDim.x + threadIdx.x;
    if (idx >= TAB_ELEMS) return;
    int l = idx >> 9;
    int slot = idx & (NANG - 1);
    int sub = slot >> 4, p = slot & 15;
    int m10 = l % 10;
    int sp = m10;
    int SL = 1 << (m10 % 5);
    int i0 = 2 * (p / SL) * SL + p % SL;
    int r = (m10 >= 5) ? rowB(sub, i0) : rowA(sub, i0);
    int a = ((r >> (sp + 1)) << sp) | (r & ((1 << sp) - 1));
    float th = ang[l * NANG + a];
    float sv, cv;
    sincosf(th, &sv, &cv);
    tab[idx] = make_float2(cv, sv);
}

__device__ __forceinline__ void rotp(v2f& a, v2f& b, float cv, float sv) {
    v2f c = {cv, cv}, s = {sv, sv};
    v2f x0 = a, x1 = b;
    a = __builtin_elementwise_fma(c, x0, s * x1);
    b = __builtin_elementwise_fma(-s, x0, c * x1);
}

template<int SL>
__device__ __forceinline__ void layer_tab(v2f y[32],
                                          const float4* __restrict__ q4) {
    #pragma unroll
    for (int v = 0; v < 8; ++v) {
        float4 q = q4[v];
        int p0 = 2 * v, p1 = 2 * v + 1;
        int a0 = 2 * (p0 / SL) * SL + p0 % SL;
        int a1 = 2 * (p1 / SL) * SL + p1 % SL;
        rotp(y[a0], y[a0 + SL], q.x, q.y);
        rotp(y[a1], y[a1 + SL], q.z, q.w);
    }
}

template<int SL, bool PB, int SP>
__device__ __forceinline__ void layer_notab(v2f y[32],
                                            const float* __restrict__ angL,
                                            int sub) {
    #pragma unroll
    for (int p = 0; p < 16; ++p) {
        int i0 = 2 * (p / SL) * SL + p % SL;
        int r = PB ? rowB(sub, i0) : rowA(sub, i0);
        int a = ((r >> (SP + 1)) << SP) | (r & ((1 << SP) - 1));
        float th = angL[a];
        float sv, cv;
        __sincosf(th, &sv, &cv);
        rotp(y[i0], y[i0 + SL], cv, sv);
    }
}

template<bool USE_TAB>
__global__ __launch_bounds__(256) void butterfly_kernel(
        const float* __restrict__ X, const float* __restrict__ ang,
        const float2* __restrict__ tab, float* __restrict__ out) {
    __shared__ v2f lds[8 * 1024];
    int t = threadIdx.x;
    int c = t & 7;
    int sub = t >> 3;
    int bid = blockIdx.x;
    int L = ((bid & 7) << 6) | (bid >> 3);
    int col2 = (L << 3) + c;
    int xr = (c & 7) << 1;
    v2f* base = lds + (c << 10);

    v2f y[32];
    const v2f* Xp = reinterpret_cast<const v2f*>(X) + col2;
    #pragma unroll
    for (int i = 0; i < 32; ++i)
        y[i] = Xp[rowA(sub, i) * BATCH2];

    const float4* tf4 = reinterpret_cast<const float4*>(tab);
    if (USE_TAB) {
        layer_tab<1 >(y, tf4 + 0 * 256 + 8 * sub);
        layer_tab<2 >(y, tf4 + 1 * 256 + 8 * sub);
        layer_tab<4 >(y, tf4 + 2 * 256 + 8 * sub);
        layer_tab<8 >(y, tf4 + 3 * 256 + 8 * sub);
        layer_tab<16>(y, tf4 + 4 * 256 + 8 * sub);
    } else {
        layer_notab<1 ,false,0>(y, ang + 0 * NANG, sub);
        layer_notab<2 ,false,1>(y, ang + 1 * NANG, sub);
        layer_notab<4 ,false,2>(y, ang + 2 * NANG, sub);
        layer_notab<8 ,false,3>(y, ang + 3 * NANG, sub);
        layer_notab<16,false,4>(y, ang + 4 * NANG, sub);
    }
    #pragma unroll
    for (int u = 0; u < 16; ++u)
        *reinterpret_cast<float4*>(&base[((sub << 5) + 2 * u) ^ xr]) =
            make_float4(y[2*u].x, y[2*u].y, y[2*u+1].x, y[2*u+1].y);
    __syncthreads();
    #pragma unroll
    for (int i = 0; i < 32; ++i) y[i] = base[rowB(sub, i) ^ xr];

    if (USE_TAB) {
        layer_tab<1 >(y, tf4 + 5 * 256 + 8 * sub);
        layer_tab<2 >(y, tf4 + 6 * 256 + 8 * sub);
        layer_tab<4 >(y, tf4 + 7 * 256 + 8 * sub);
        layer_tab<8 >(y, tf4 + 8 * 256 + 8 * sub);
        layer_tab<16>(y, tf4 + 9 * 256 + 8 * sub);
    } else {
        layer_notab<1 ,true,5>(y, ang + 5 * NANG, sub);
        layer_notab<2 ,true,6>(y, ang + 6 * NANG, sub);
        layer_notab<4 ,true,7>(y, ang + 7 * NANG, sub);
        layer_notab<8 ,true,8>(y, ang + 8 * NANG, sub);
        layer_notab<16,true,9>(y, ang + 9 * NANG, sub);
    }
    __syncthreads();
    #pragma unroll
    for (int i = 0; i < 32; ++i) base[rowB(sub, i) ^ xr] = y[i];
    __syncthreads();
    #pragma unroll
    for (int u = 0; u < 16; ++u) {
        float4 v = *reinterpret_cast<const float4*>(&base[((sub << 5) + 2 * u) ^ xr]);
        y[2*u].x = v.x; y[2*u].y = v.y; y[2*u+1].x = v.z; y[2*u+1].y = v.w;
    }

    if (USE_TAB) {
        layer_tab<1 >(y, tf4 + 10 * 256 + 8 * sub);
        layer_tab<2 >(y, tf4 + 11 * 256 + 8 * sub);
        layer_tab<4 >(y, tf4 + 12 * 256 + 8 * sub);
        layer_tab<8 >(y, tf4 + 13 * 256 + 8 * sub);
        layer_tab<16>(y, tf4 + 14 * 256 + 8 * sub);
    } else {
        layer_notab<1 ,false,0>(y, ang + 10 * NANG, sub);
        layer_notab<2 ,false,1>(y, ang + 11 * NANG, sub);
        layer_notab<4 ,false,2>(y, ang + 12 * NANG, sub);
        layer_notab<8 ,false,3>(y, ang + 13 * NANG, sub);
        layer_notab<16,false,4>(y, ang + 14 * NANG, sub);
    }
    __syncthreads();
    #pragma unroll
    for (int u = 0; u < 16; ++u)
        *reinterpret_cast<float4*>(&base[((sub << 5) + 2 * u) ^ xr]) =
            make_float4(y[2*u].x, y[2*u].y, y[2*u+1].x, y[2*u+1].y);
    __syncthreads();
    #pragma unroll
    for (int i = 0; i < 32; ++i) y[i] = base[rowB(sub, i) ^ xr];

    if (USE_TAB) {
        layer_tab<1 >(y, tf4 + 15 * 256 + 8 * sub);
        layer_tab<2 >(y, tf4 + 16 * 256 + 8 * sub);
        layer_tab<4 >(y, tf4 + 17 * 256 + 8 * sub);
        layer_tab<8 >(y, tf4 + 18 * 256 + 8 * sub);
        layer_tab<16>(y, tf4 + 19 * 256 + 8 * sub);
    } else {
        layer_notab<1 ,true,5>(y, ang + 15 * NANG, sub);
        layer_notab<2 ,true,6>(y, ang + 16 * NANG, sub);
        layer_notab<4 ,true,7>(y, ang + 17 * NANG, sub);
        layer_notab<8 ,true,8>(y, ang + 18 * NANG, sub);
        layer_notab<16,true,9>(y, ang + 19 * NANG, sub);
    }

    v2f* Op = reinterpret_cast<v2f*>(out) + col2;
    #pragma unroll
    for (int i = 0; i < 32; ++i)
        Op[rowB(sub, i) * BATCH2] = y[i];
}

extern "C" void kernel_launch(void* const* d_in, const int* in_sizes, int n_in,
                              void* d_out, int out_size, void* d_ws, size_t ws_size,
                              hipStream_t stream) {
    (void)in_sizes; (void)n_in; (void)out_size;
    const float* X   = (const float*)d_in[0];
    const float* ang = (const float*)d_in[1];
    float* out = (float*)d_out;

    if (d_ws != nullptr && ws_size >= WS_MFMA_BYTES) {
        unsigned short* whi = (unsigned short*)d_ws;
        unsigned short* wlo = whi + 4 * 32 * 1024;
        build_w_kernel<<<64, 64, 0, stream>>>(ang, whi, wlo);
        mfma_kernel<<<512, 256, 0, stream>>>(X, whi, wlo, out);
    } else if (d_ws != nullptr && ws_size >= TAB_BYTES) {
        float2* tab = (float2*)d_ws;
        build_tab_kernel<<<(TAB_ELEMS + 255) / 256, 256, 0, stream>>>(ang, tab);
        butterfly_kernel<true><<<512, 256, 0, stream>>>(X, ang, tab, out);
    } else {
        butterfly_kernel<false><<<512, 256, 0, stream>>>(X, ang, nullptr, out);
    }
}

// Round 21
// 29.221 us; speedup vs baseline: 1.1964x; 1.1964x over previous
//
#include <hip/hip_runtime.h>
#include <math.h>

// OrthogonalButterfly: X (1024 x 8192) fp32, 20 butterfly layers, stride 2^(l%10).
// R19 = 29.46us best. R20 (16-col) regressed: W traffic doubled (+4-7us).
// R21: (1) single-W bf16 (drop lo chain): halves MFMA + W traffic -> 16-col
//      grid-512 gets 2 blocks/CU at R19's W traffic. absmax est ~0.05 < 0.114.
//      (2) wave w owns sites rb=8w..8w+7: boundary values accumulate in regs
//      (pk[4][4], static) -> 8 clean b128 writes replace 64 conflicted b16
//      scatters (bit-identical destination bytes; rb>>3=w, rb&7=m).
//      (3) entry loads f2 col-pairs (32 dwordx2 vs 64 scalar).
// Fallback: R15 tab/notab paths if ws_size < 512KB.

#define NROW   1024
#define BATCH  8192
#define BATCH2 (BATCH / 2)
#define DEPTH  20
#define NANG   512
#define TAB_ELEMS (DEPTH * NANG)
#define TAB_BYTES ((size_t)TAB_ELEMS * 8)
#define WS_MFMA_BYTES ((size_t)(4 * 32 * 1024) * 2 * 2)   // hi+lo, 512KB

typedef float v2f __attribute__((ext_vector_type(2)));
using bf16x8 = __attribute__((ext_vector_type(8))) short;
using f32x4  = __attribute__((ext_vector_type(4))) float;

__device__ __forceinline__ unsigned short f2b(float f) {
    union { float f; unsigned int u; } v; v.f = f;
    unsigned int u = v.u;
    return (unsigned short)((u + 0x7FFFu + ((u >> 16) & 1u)) >> 16);
}
__device__ __forceinline__ float b2f(unsigned short b) {
    union { unsigned int u; float f; } v; v.u = ((unsigned int)b) << 16;
    return v.f;
}

// ================= MFMA path =================
// W[grp][b] 32x32 row-major: column j = 5 butterfly layers applied to e_j.
// Builder (R18-proven): wave widx handles matrices (grp, bpair*2+{0,1}).
__global__ __launch_bounds__(64) void build_w_kernel(
        const float* __restrict__ ang,
        unsigned short* __restrict__ whi,
        unsigned short* __restrict__ wlo) {
    __shared__ float2 cs[160];           // [h*80 + q*16 + p]
    int ln = threadIdx.x;                // [0,64)
    int widx = blockIdx.x;               // [0,64)
    int grp = widx >> 4;                 // [0,4)
    int bpair = widx & 15;               // [0,16)

    #pragma unroll
    for (int rnd = 0; rnd < 3; ++rnd) {
        int tt = ln + rnd * 64;
        if (tt < 160) {
            int h = tt >= 80;
            int u = tt - h * 80;
            int q = u >> 4, p = u & 15;
            int b = bpair * 2 + h;
            int sp = (grp & 1) ? q + 5 : q;
            int l  = grp * 5 + q;
            int s  = 1 << sp;
            int SL = 1 << q;
            int i0 = ((p >> q) << (q + 1)) | (p & (SL - 1));
            int r0 = (grp & 1) ? ((i0 << 5) | b) : ((b << 5) | i0);
            int a  = ((r0 >> (sp + 1)) << sp) | (r0 & (s - 1));
            float th = ang[l * NANG + a];
            float sv, cv;
            __sincosf(th, &sv, &cv);
            cs[tt] = make_float2(cv, sv);
        }
    }
    __syncthreads();

    int h = ln >> 5, j = ln & 31;
    int b = bpair * 2 + h;
    float v[32];
    #pragma unroll
    for (int i = 0; i < 32; ++i) v[i] = (i == j) ? 1.f : 0.f;
    #pragma unroll
    for (int q = 0; q < 5; ++q) {
        int SL = 1 << q;
        #pragma unroll
        for (int p = 0; p < 16; ++p) {
            int i0 = ((p >> q) << (q + 1)) | (p & (SL - 1));
            int i1 = i0 + SL;
            float2 q2 = cs[h * 80 + q * 16 + p];   // broadcast read
            float x0 = v[i0], x1 = v[i1];
            v[i0] = q2.x * x0 + q2.y * x1;
            v[i1] = q2.x * x1 - q2.y * x0;
        }
    }
    int mat = grp * 32 + b;
    #pragma unroll
    for (int i = 0; i < 32; ++i) {
        unsigned short hh = f2b(v[i]);
        whi[mat * 1024 + i * 32 + j] = hh;               // coalesced 64B/half
        wlo[mat * 1024 + i * 32 + j] = f2b(v[i] - b2f(hh));
    }
}

// Tile layout (bf16): ushort idx = site*512 + (k>>3)*128 + cc*8 + (k&7)
//   site = rb (32 sites x 1KB = 32KB)
__global__ __launch_bounds__(256, 4) void mfma_kernel(
        const float* __restrict__ X,
        const unsigned short* __restrict__ whi,
        float* __restrict__ out) {
    __shared__ __align__(16) unsigned short sbuf[16384];   // 32KB
    int t  = threadIdx.x;
    int ln = t & 63;
    int w  = t >> 6;                          // wave id [0,4)
    int bid = blockIdx.x;
    int L = ((bid & 7) << 6) | (bid >> 3);    // XCD swizzle, bijective (512=8*64)
    int col0 = L << 4;                        // 16 cols per block

    // ---- entry: fp32 global (f2 col-pairs) -> bf16 tiles ----
    {
        int cp = t & 7;                       // col-pair [0,8)
        int bb = t >> 3;                      // [0,32)
        int base2 = (col0 >> 1) + cp;         // v2f index of (row 0, col 2cp)
        const v2f* X2 = reinterpret_cast<const v2f*>(X);
        #pragma unroll
        for (int it = 0; it < 16; ++it) {
            int r = 2 * bb + 64 * it;         // even row; pair (r, r+1)
            v2f a = X2[r * BATCH2 + base2];
            v2f b = X2[(r + 1) * BATCH2 + base2];
            int rb = r >> 5, k = r & 31;      // k even
            int idx = rb * 512 + (k >> 3) * 128 + (k & 7);
            unsigned int u0 = (unsigned int)f2b(a.x) | ((unsigned int)f2b(b.x) << 16);
            unsigned int u1 = (unsigned int)f2b(a.y) | ((unsigned int)f2b(b.y) << 16);
            *reinterpret_cast<unsigned int*>(&sbuf[idx + (2 * cp) * 8])     = u0;
            *reinterpret_cast<unsigned int*>(&sbuf[idx + (2 * cp + 1) * 8]) = u1;
        }
    }
    __syncthreads();

    const bf16x8* WH = reinterpret_cast<const bf16x8*>(whi);
    int r15 = ln & 15, kg = ln >> 4;

    #pragma unroll
    for (int grp = 0; grp < 4; ++grp) {
        // ---- batched reads: 8 B-fragments (sites rb = 8w..8w+7) ----
        bf16x8 bf[8];
        #pragma unroll
        for (int m = 0; m < 8; ++m) {
            int rb = w * 8 + m;
            bf[m] = *reinterpret_cast<const bf16x8*>(
                &sbuf[rb * 512 + kg * 128 + r15 * 8]);
        }
        if (grp < 3) {
            __syncthreads();                 // reads done before any write
            unsigned int pk0[4][4], pk1[4][4];   // [e][m>>1], static idx
            #pragma unroll
            for (int m = 0; m < 8; ++m) {
                int rb  = w * 8 + m;
                int mat = grp * 32 + rb;
                bf16x8 ah0 = WH[mat * 128 + (r15     ) * 4 + kg];
                bf16x8 ah1 = WH[mat * 128 + (r15 + 16) * 4 + kg];
                f32x4 acc0 = {0.f, 0.f, 0.f, 0.f};
                f32x4 acc1 = {0.f, 0.f, 0.f, 0.f};
                acc0 = __builtin_amdgcn_mfma_f32_16x16x32_bf16(ah0, bf[m], acc0, 0, 0, 0);
                acc1 = __builtin_amdgcn_mfma_f32_16x16x32_bf16(ah1, bf[m], acc1, 0, 0, 0);
                #pragma unroll
                for (int e = 0; e < 4; ++e) {
                    unsigned int b0 = f2b(acc0[e]);
                    unsigned int b1 = f2b(acc1[e]);
                    if ((m & 1) == 0) { pk0[e][m >> 1] = b0;        pk1[e][m >> 1] = b1; }
                    else              { pk0[e][m >> 1] |= b0 << 16; pk1[e][m >> 1] |= b1 << 16; }
                }
            }
            // boundary: site' = old row k, k'-octet = w, k'&7 = m (b128, clean)
            #pragma unroll
            for (int e = 0; e < 4; ++e) {
                int s0 = kg * 4 + e, s1 = 16 + kg * 4 + e;
                *reinterpret_cast<uint4*>(&sbuf[s0 * 512 + w * 128 + r15 * 8]) =
                    make_uint4(pk0[e][0], pk0[e][1], pk0[e][2], pk0[e][3]);
                *reinterpret_cast<uint4*>(&sbuf[s1 * 512 + w * 128 + r15 * 8]) =
                    make_uint4(pk1[e][0], pk1[e][1], pk1[e][2], pk1[e][3]);
            }
            __syncthreads();                 // writes done before next reads
        } else {
            // G3 is B-space: r = k*32 + rb; direct coalesced store
            #pragma unroll
            for (int m = 0; m < 8; ++m) {
                int rb  = w * 8 + m;
                int mat = grp * 32 + rb;
                bf16x8 ah0 = WH[mat * 128 + (r15     ) * 4 + kg];
                bf16x8 ah1 = WH[mat * 128 + (r15 + 16) * 4 + kg];
                f32x4 acc0 = {0.f, 0.f, 0.f, 0.f};
                f32x4 acc1 = {0.f, 0.f, 0.f, 0.f};
                acc0 = __builtin_amdgcn_mfma_f32_16x16x32_bf16(ah0, bf[m], acc0, 0, 0, 0);
                acc1 = __builtin_amdgcn_mfma_f32_16x16x32_bf16(ah1, bf[m], acc1, 0, 0, 0);
                int col = col0 + r15;
                #pragma unroll
                for (int e = 0; e < 4; ++e) {
                    int r0 = (kg * 4 + e) * 32 + rb;
                    int r1 = (16 + kg * 4 + e) * 32 + rb;
                    out[r0 * BATCH + col] = acc0[e];
                    out[r1 * BATCH + col] = acc1[e];
                }
            }
        }
    }
}

// ================= fallback: R15 path (proven 31.6us) =================
__device__ __host__ __forceinline__ int rowA(int sub, int i){ return (sub << 5) | i; }
__device__ __host__ __forceinline__ int rowB(int sub, int i){ return sub | (i << 5); }

__global__ void build_tab_kernel(const float* __restrict__ ang,
                                 float2* __restrict__ tab) {
    int idx = blockIdx.x * blockDim.x + threadIdx.x;
    if (idx >= TAB_ELEMS) return;
    int l = idx >> 9;
    int slot = idx & (NANG - 1);
    int sub = slot >> 4, p = slot & 15;
    int m10 = l % 10;
    int sp = m10;
    int SL = 1 << (m10 % 5);
    int i0 = 2 * (p / SL) * SL + p % SL;
    int r = (m10 >= 5) ? rowB(sub, i0) : rowA(sub, i0);
    int a = ((r >> (sp + 1)) << sp) | (r & ((1 << sp) - 1));
    float th = ang[l * NANG + a];
    float sv, cv;
    sincosf(th, &sv, &cv);
    tab[idx] = make_float2(cv, sv);
}

__device__ __forceinline__ void rotp(v2f& a, v2f& b, float cv, float sv) {
    v2f c = {cv, cv}, s = {sv, sv};
    v2f x0 = a, x1 = b;
    a = __builtin_elementwise_fma(c, x0, s * x1);
    b = __builtin_elementwise_fma(-s, x0, c * x1);
}

template<int SL>
__device__ __forceinline__ void layer_tab(v2f y[32],
                                          const float4* __restrict__ q4) {
    #pragma unroll
    for (int v = 0; v < 8; ++v) {
        float4 q = q4[v];
        int p0 = 2 * v, p1 = 2 * v + 1;
        int a0 = 2 * (p0 / SL) * SL + p0 % SL;
        int a1 = 2 * (p1 / SL) * SL + p1 % SL;
        rotp(y[a0], y[a0 + SL], q.x, q.y);
        rotp(y[a1], y[a1 + SL], q.z, q.w);
    }
}

template<int SL, bool PB, int SP>
__device__ __forceinline__ void layer_notab(v2f y[32],
                                            const float* __restrict__ angL,
                                            int sub) {
    #pragma unroll
    for (int p = 0; p < 16; ++p) {
        int i0 = 2 * (p / SL) * SL + p % SL;
        int r = PB ? rowB(sub, i0) : rowA(sub, i0);
        int a = ((r >> (SP + 1)) << SP) | (r & ((1 << SP) - 1));
        float th = angL[a];
        float sv, cv;
        __sincosf(th, &sv, &cv);
        rotp(y[i0], y[i0 + SL], cv, sv);
    }
}

template<bool USE_TAB>
__global__ __launch_bounds__(256) void butterfly_kernel(
        const float* __restrict__ X, const float* __restrict__ ang,
        const float2* __restrict__ tab, float* __restrict__ out) {
    __shared__ v2f lds[8 * 1024];
    int t = threadIdx.x;
    int c = t & 7;
    int sub = t >> 3;
    int bid = blockIdx.x;
    int L = ((bid & 7) << 6) | (bid >> 3);
    int col2 = (L << 3) + c;
    int xr = (c & 7) << 1;
    v2f* base = lds + (c << 10);

    v2f y[32];
    const v2f* Xp = reinterpret_cast<const v2f*>(X) + col2;
    #pragma unroll
    for (int i = 0; i < 32; ++i)
        y[i] = Xp[rowA(sub, i) * BATCH2];

    const float4* tf4 = reinterpret_cast<const float4*>(tab);
    if (USE_TAB) {
        layer_tab<1 >(y, tf4 + 0 * 256 + 8 * sub);
        layer_tab<2 >(y, tf4 + 1 * 256 + 8 * sub);
        layer_tab<4 >(y, tf4 + 2 * 256 + 8 * sub);
        layer_tab<8 >(y, tf4 + 3 * 256 + 8 * sub);
        layer_tab<16>(y, tf4 + 4 * 256 + 8 * sub);
    } else {
        layer_notab<1 ,false,0>(y, ang + 0 * NANG, sub);
        layer_notab<2 ,false,1>(y, ang + 1 * NANG, sub);
        layer_notab<4 ,false,2>(y, ang + 2 * NANG, sub);
        layer_notab<8 ,false,3>(y, ang + 3 * NANG, sub);
        layer_notab<16,false,4>(y, ang + 4 * NANG, sub);
    }
    #pragma unroll
    for (int u = 0; u < 16; ++u)
        *reinterpret_cast<float4*>(&base[((sub << 5) + 2 * u) ^ xr]) =
            make_float4(y[2*u].x, y[2*u].y, y[2*u+1].x, y[2*u+1].y);
    __syncthreads();
    #pragma unroll
    for (int i = 0; i < 32; ++i) y[i] = base[rowB(sub, i) ^ xr];

    if (USE_TAB) {
        layer_tab<1 >(y, tf4 + 5 * 256 + 8 * sub);
        layer_tab<2 >(y, tf4 + 6 * 256 + 8 * sub);
        layer_tab<4 >(y, tf4 + 7 * 256 + 8 * sub);
        layer_tab<8 >(y, tf4 + 8 * 256 + 8 * sub);
        layer_tab<16>(y, tf4 + 9 * 256 + 8 * sub);
    } else {
        layer_notab<1 ,true,5>(y, ang + 5 * NANG, sub);
        layer_notab<2 ,true,6>(y, ang + 6 * NANG, sub);
        layer_notab<4 ,true,7>(y, ang + 7 * NANG, sub);
        layer_notab<8 ,true,8>(y, ang + 8 * NANG, sub);
        layer_notab<16,true,9>(y, ang + 9 * NANG, sub);
    }
    __syncthreads();
    #pragma unroll
    for (int i = 0; i < 32; ++i) base[rowB(sub, i) ^ xr] = y[i];
    __syncthreads();
    #pragma unroll
    for (int u = 0; u < 16; ++u) {
        float4 v = *reinterpret_cast<const float4*>(&base[((sub << 5) + 2 * u) ^ xr]);
        y[2*u].x = v.x; y[2*u].y = v.y; y[2*u+1].x = v.z; y[2*u+1].y = v.w;
    }

    if (USE_TAB) {
        layer_tab<1 >(y, tf4 + 10 * 256 + 8 * sub);
        layer_tab<2 >(y, tf4 + 11 * 256 + 8 * sub);
        layer_tab<4 >(y, tf4 + 12 * 256 + 8 * sub);
        layer_tab<8 >(y, tf4 + 13 * 256 + 8 * sub);
        layer_tab<16>(y, tf4 + 14 * 256 + 8 * sub);
    } else {
        layer_notab<1 ,false,0>(y, ang + 10 * NANG, sub);
        layer_notab<2 ,false,1>(y, ang + 11 * NANG, sub);
        layer_notab<4 ,false,2>(y, ang + 12 * NANG, sub);
        layer_notab<8 ,false,3>(y, ang + 13 * NANG, sub);
        layer_notab<16,false,4>(y, ang + 14 * NANG, sub);
    }
    __syncthreads();
    #pragma unroll
    for (int u = 0; u < 16; ++u)
        *reinterpret_cast<float4*>(&base[((sub << 5) + 2 * u) ^ xr]) =
            make_float4(y[2*u].x, y[2*u].y, y[2*u+1].x, y[2*u+1].y);
    __syncthreads();
    #pragma unroll
    for (int i = 0; i < 32; ++i) y[i] = base[rowB(sub, i) ^ xr];

    if (USE_TAB) {
        layer_tab<1 >(y, tf4 + 15 * 256 + 8 * sub);
        layer_tab<2 >(y, tf4 + 16 * 256 + 8 * sub);
        layer_tab<4 >(y, tf4 + 17 * 256 + 8 * sub);
        layer_tab<8 >(y, tf4 + 18 * 256 + 8 * sub);
        layer_tab<16>(y, tf4 + 19 * 256 + 8 * sub);
    } else {
        layer_notab<1 ,true,5>(y, ang + 15 * NANG, sub);
        layer_notab<2 ,true,6>(y, ang + 16 * NANG, sub);
        layer_notab<4 ,true,7>(y, ang + 17 * NANG, sub);
        layer_notab<8 ,true,8>(y, ang + 18 * NANG, sub);
        layer_notab<16,true,9>(y, ang + 19 * NANG, sub);
    }

    v2f* Op = reinterpret_cast<v2f*>(out) + col2;
    #pragma unroll
    for (int i = 0; i < 32; ++i)
        Op[rowB(sub, i) * BATCH2] = y[i];
}

extern "C" void kernel_launch(void* const* d_in, const int* in_sizes, int n_in,
                              void* d_out, int out_size, void* d_ws, size_t ws_size,
                              hipStream_t stream) {
    (void)in_sizes; (void)n_in; (void)out_size;
    const float* X   = (const float*)d_in[0];
    const float* ang = (const float*)d_in[1];
    float* out = (float*)d_out;

    if (d_ws != nullptr && ws_size >= WS_MFMA_BYTES) {
        unsigned short* whi = (unsigned short*)d_ws;
        unsigned short* wlo = whi + 4 * 32 * 1024;
        build_w_kernel<<<64, 64, 0, stream>>>(ang, whi, wlo);
        mfma_kernel<<<512, 256, 0, stream>>>(X, whi, out);
    } else if (d_ws != nullptr && ws_size >= TAB_BYTES) {
        float2* tab = (float2*)d_ws;
        build_tab_kernel<<<(TAB_ELEMS + 255) / 256, 256, 0, stream>>>(ang, tab);
        butterfly_kernel<true><<<512, 256, 0, stream>>>(X, ang, tab, out);
    } else {
        butterfly_kernel<false><<<512, 256, 0, stream>>>(X, ang, nullptr, out);
    }
}

// Round 22
// 27.940 us; speedup vs baseline: 1.2512x; 1.0458x over previous
//
#include <hip/hip_runtime.h>
#include <math.h>

// OrthogonalButterfly: X (1024 x 8192) fp32, 20 butterfly layers, stride 2^(l%10).
// R21 = 29.2us best (single-W bf16, reg-packed b128 boundary writes, 16-col
// blocks, grid 512). Occupancy 18.9% == ~75% of the CONFIGURED 8 waves/CU cap.
// R22: same footprint (16 cols, 32KB LDS, grid 512 -> 2 blocks/CU, W traffic
// unchanged) but 512 thr = 8 waves/block, 4 sites/wave (rb=4w+m) -> 16
// waves/CU (50% cap), half the per-thread serial work. Boundary writes b64
// (half-octets at 4(w&1); 2-way bank aliasing = free). Bytes bit-identical.
// Fallback: R15 tab/notab paths if ws_size < 512KB.

#define NROW   1024
#define BATCH  8192
#define BATCH2 (BATCH / 2)
#define DEPTH  20
#define NANG   512
#define TAB_ELEMS (DEPTH * NANG)
#define TAB_BYTES ((size_t)TAB_ELEMS * 8)
#define WS_MFMA_BYTES ((size_t)(4 * 32 * 1024) * 2 * 2)   // hi+lo, 512KB

typedef float v2f __attribute__((ext_vector_type(2)));
using bf16x8 = __attribute__((ext_vector_type(8))) short;
using f32x4  = __attribute__((ext_vector_type(4))) float;

__device__ __forceinline__ unsigned short f2b(float f) {
    union { float f; unsigned int u; } v; v.f = f;
    unsigned int u = v.u;
    return (unsigned short)((u + 0x7FFFu + ((u >> 16) & 1u)) >> 16);
}
__device__ __forceinline__ float b2f(unsigned short b) {
    union { unsigned int u; float f; } v; v.u = ((unsigned int)b) << 16;
    return v.f;
}

// ================= MFMA path =================
// W[grp][b] 32x32 row-major: column j = 5 butterfly layers applied to e_j.
// Builder (R18-proven): wave widx handles matrices (grp, bpair*2+{0,1}).
__global__ __launch_bounds__(64) void build_w_kernel(
        const float* __restrict__ ang,
        unsigned short* __restrict__ whi,
        unsigned short* __restrict__ wlo) {
    __shared__ float2 cs[160];           // [h*80 + q*16 + p]
    int ln = threadIdx.x;                // [0,64)
    int widx = blockIdx.x;               // [0,64)
    int grp = widx >> 4;                 // [0,4)
    int bpair = widx & 15;               // [0,16)

    #pragma unroll
    for (int rnd = 0; rnd < 3; ++rnd) {
        int tt = ln + rnd * 64;
        if (tt < 160) {
            int h = tt >= 80;
            int u = tt - h * 80;
            int q = u >> 4, p = u & 15;
            int b = bpair * 2 + h;
            int sp = (grp & 1) ? q + 5 : q;
            int l  = grp * 5 + q;
            int s  = 1 << sp;
            int SL = 1 << q;
            int i0 = ((p >> q) << (q + 1)) | (p & (SL - 1));
            int r0 = (grp & 1) ? ((i0 << 5) | b) : ((b << 5) | i0);
            int a  = ((r0 >> (sp + 1)) << sp) | (r0 & (s - 1));
            float th = ang[l * NANG + a];
            float sv, cv;
            __sincosf(th, &sv, &cv);
            cs[tt] = make_float2(cv, sv);
        }
    }
    __syncthreads();

    int h = ln >> 5, j = ln & 31;
    int b = bpair * 2 + h;
    float v[32];
    #pragma unroll
    for (int i = 0; i < 32; ++i) v[i] = (i == j) ? 1.f : 0.f;
    #pragma unroll
    for (int q = 0; q < 5; ++q) {
        int SL = 1 << q;
        #pragma unroll
        for (int p = 0; p < 16; ++p) {
            int i0 = ((p >> q) << (q + 1)) | (p & (SL - 1));
            int i1 = i0 + SL;
            float2 q2 = cs[h * 80 + q * 16 + p];   // broadcast read
            float x0 = v[i0], x1 = v[i1];
            v[i0] = q2.x * x0 + q2.y * x1;
            v[i1] = q2.x * x1 - q2.y * x0;
        }
    }
    int mat = grp * 32 + b;
    #pragma unroll
    for (int i = 0; i < 32; ++i) {
        unsigned short hh = f2b(v[i]);
        whi[mat * 1024 + i * 32 + j] = hh;               // coalesced 64B/half
        wlo[mat * 1024 + i * 32 + j] = f2b(v[i] - b2f(hh));
    }
}

// Tile layout (bf16): ushort idx = site*512 + (k>>3)*128 + cc*8 + (k&7)
//   site = rb (32 sites x 1KB = 32KB)
__global__ __launch_bounds__(512, 4) void mfma_kernel(
        const float* __restrict__ X,
        const unsigned short* __restrict__ whi,
        float* __restrict__ out) {
    __shared__ __align__(16) unsigned short sbuf[16384];   // 32KB
    int t  = threadIdx.x;
    int ln = t & 63;
    int w  = t >> 6;                          // wave id [0,8)
    int bid = blockIdx.x;
    int L = ((bid & 7) << 6) | (bid >> 3);    // XCD swizzle, bijective (512=8*64)
    int col0 = L << 4;                        // 16 cols per block

    // ---- entry: fp32 global (f2 col-pairs) -> bf16 tiles ----
    {
        int cp = t & 7;                       // col-pair [0,8)
        int bb = t >> 3;                      // [0,64)
        int base2 = (col0 >> 1) + cp;         // v2f index of (row 0, col 2cp)
        const v2f* X2 = reinterpret_cast<const v2f*>(X);
        #pragma unroll
        for (int it = 0; it < 8; ++it) {
            int r = 2 * bb + 128 * it;        // even row; pair (r, r+1)
            v2f a = X2[r * BATCH2 + base2];
            v2f b = X2[(r + 1) * BATCH2 + base2];
            int rb = r >> 5, k = r & 31;      // k even
            int idx = rb * 512 + (k >> 3) * 128 + (k & 7);
            unsigned int u0 = (unsigned int)f2b(a.x) | ((unsigned int)f2b(b.x) << 16);
            unsigned int u1 = (unsigned int)f2b(a.y) | ((unsigned int)f2b(b.y) << 16);
            *reinterpret_cast<unsigned int*>(&sbuf[idx + (2 * cp) * 8])     = u0;
            *reinterpret_cast<unsigned int*>(&sbuf[idx + (2 * cp + 1) * 8]) = u1;
        }
    }
    __syncthreads();

    const bf16x8* WH = reinterpret_cast<const bf16x8*>(whi);
    int r15 = ln & 15, kg = ln >> 4;

    #pragma unroll
    for (int grp = 0; grp < 4; ++grp) {
        // ---- batched reads: 4 B-fragments (sites rb = 4w..4w+3) ----
        bf16x8 bf[4];
        #pragma unroll
        for (int m = 0; m < 4; ++m) {
            int rb = w * 4 + m;
            bf[m] = *reinterpret_cast<const bf16x8*>(
                &sbuf[rb * 512 + kg * 128 + r15 * 8]);
        }
        if (grp < 3) {
            __syncthreads();                 // reads done before any write
            uint2 pk0[4], pk1[4];            // [e]: 4 bf16 for k' = 4w..4w+3
            #pragma unroll
            for (int m = 0; m < 4; ++m) {
                int rb  = w * 4 + m;
                int mat = grp * 32 + rb;
                bf16x8 ah0 = WH[mat * 128 + (r15     ) * 4 + kg];
                bf16x8 ah1 = WH[mat * 128 + (r15 + 16) * 4 + kg];
                f32x4 acc0 = {0.f, 0.f, 0.f, 0.f};
                f32x4 acc1 = {0.f, 0.f, 0.f, 0.f};
                acc0 = __builtin_amdgcn_mfma_f32_16x16x32_bf16(ah0, bf[m], acc0, 0, 0, 0);
                acc1 = __builtin_amdgcn_mfma_f32_16x16x32_bf16(ah1, bf[m], acc1, 0, 0, 0);
                #pragma unroll
                for (int e = 0; e < 4; ++e) {
                    unsigned int b0 = f2b(acc0[e]);
                    unsigned int b1 = f2b(acc1[e]);
                    if (m == 0)      { pk0[e].x = b0;        pk1[e].x = b1; }
                    else if (m == 1) { pk0[e].x |= b0 << 16; pk1[e].x |= b1 << 16; }
                    else if (m == 2) { pk0[e].y = b0;        pk1[e].y = b1; }
                    else             { pk0[e].y |= b0 << 16; pk1[e].y |= b1 << 16; }
                }
            }
            // boundary: site' = old row k; k' = rb: octet w>>1, half 4(w&1)
            int off = (w >> 1) * 128 + r15 * 8 + 4 * (w & 1);
            #pragma unroll
            for (int e = 0; e < 4; ++e) {
                int s0 = kg * 4 + e, s1 = 16 + kg * 4 + e;
                *reinterpret_cast<uint2*>(&sbuf[s0 * 512 + off]) = pk0[e];
                *reinterpret_cast<uint2*>(&sbuf[s1 * 512 + off]) = pk1[e];
            }
            __syncthreads();                 // writes done before next reads
        } else {
            // G3 is B-space: r = k*32 + rb; direct coalesced store
            #pragma unroll
            for (int m = 0; m < 4; ++m) {
                int rb  = w * 4 + m;
                int mat = grp * 32 + rb;
                bf16x8 ah0 = WH[mat * 128 + (r15     ) * 4 + kg];
                bf16x8 ah1 = WH[mat * 128 + (r15 + 16) * 4 + kg];
                f32x4 acc0 = {0.f, 0.f, 0.f, 0.f};
                f32x4 acc1 = {0.f, 0.f, 0.f, 0.f};
                acc0 = __builtin_amdgcn_mfma_f32_16x16x32_bf16(ah0, bf[m], acc0, 0, 0, 0);
                acc1 = __builtin_amdgcn_mfma_f32_16x16x32_bf16(ah1, bf[m], acc1, 0, 0, 0);
                int col = col0 + r15;
                #pragma unroll
                for (int e = 0; e < 4; ++e) {
                    int r0 = (kg * 4 + e) * 32 + rb;
                    int r1 = (16 + kg * 4 + e) * 32 + rb;
                    out[r0 * BATCH + col] = acc0[e];
                    out[r1 * BATCH + col] = acc1[e];
                }
            }
        }
    }
}

// ================= fallback: R15 path (proven 31.6us) =================
__device__ __host__ __forceinline__ int rowA(int sub, int i){ return (sub << 5) | i; }
__device__ __host__ __forceinline__ int rowB(int sub, int i){ return sub | (i << 5); }

__global__ void build_tab_kernel(const float* __restrict__ ang,
                                 float2* __restrict__ tab) {
    int idx = blockIdx.x * blockDim.x + threadIdx.x;
    if (idx >= TAB_ELEMS) return;
    int l = idx >> 9;
    int slot = idx & (NANG - 1);
    int sub = slot >> 4, p = slot & 15;
    int m10 = l % 10;
    int sp = m10;
    int SL = 1 << (m10 % 5);
    int i0 = 2 * (p / SL) * SL + p % SL;
    int r = (m10 >= 5) ? rowB(sub, i0) : rowA(sub, i0);
    int a = ((r >> (sp + 1)) << sp) | (r & ((1 << sp) - 1));
    float th = ang[l * NANG + a];
    float sv, cv;
    sincosf(th, &sv, &cv);
    tab[idx] = make_float2(cv, sv);
}

__device__ __forceinline__ void rotp(v2f& a, v2f& b, float cv, float sv) {
    v2f c = {cv, cv}, s = {sv, sv};
    v2f x0 = a, x1 = b;
    a = __builtin_elementwise_fma(c, x0, s * x1);
    b = __builtin_elementwise_fma(-s, x0, c * x1);
}

template<int SL>
__device__ __forceinline__ void layer_tab(v2f y[32],
                                          const float4* __restrict__ q4) {
    #pragma unroll
    for (int v = 0; v < 8; ++v) {
        float4 q = q4[v];
        int p0 = 2 * v, p1 = 2 * v + 1;
        int a0 = 2 * (p0 / SL) * SL + p0 % SL;
        int a1 = 2 * (p1 / SL) * SL + p1 % SL;
        rotp(y[a0], y[a0 + SL], q.x, q.y);
        rotp(y[a1], y[a1 + SL], q.z, q.w);
    }
}

template<int SL, bool PB, int SP>
__device__ __forceinline__ void layer_notab(v2f y[32],
                                            const float* __restrict__ angL,
                                            int sub) {
    #pragma unroll
    for (int p = 0; p < 16; ++p) {
        int i0 = 2 * (p / SL) * SL + p % SL;
        int r = PB ? rowB(sub, i0) : rowA(sub, i0);
        int a = ((r >> (SP + 1)) << SP) | (r & ((1 << SP) - 1));
        float th = angL[a];
        float sv, cv;
        __sincosf(th, &sv, &cv);
        rotp(y[i0], y[i0 + SL], cv, sv);
    }
}

template<bool USE_TAB>
__global__ __launch_bounds__(256) void butterfly_kernel(
        const float* __restrict__ X, const float* __restrict__ ang,
        const float2* __restrict__ tab, float* __restrict__ out) {
    __shared__ v2f lds[8 * 1024];
    int t = threadIdx.x;
    int c = t & 7;
    int sub = t >> 3;
    int bid = blockIdx.x;
    int L = ((bid & 7) << 6) | (bid >> 3);
    int col2 = (L << 3) + c;
    int xr = (c & 7) << 1;
    v2f* base = lds + (c << 10);

    v2f y[32];
    const v2f* Xp = reinterpret_cast<const v2f*>(X) + col2;
    #pragma unroll
    for (int i = 0; i < 32; ++i)
        y[i] = Xp[rowA(sub, i) * BATCH2];

    const float4* tf4 = reinterpret_cast<const float4*>(tab);
    if (USE_TAB) {
        layer_tab<1 >(y, tf4 + 0 * 256 + 8 * sub);
        layer_tab<2 >(y, tf4 + 1 * 256 + 8 * sub);
        layer_tab<4 >(y, tf4 + 2 * 256 + 8 * sub);
        layer_tab<8 >(y, tf4 + 3 * 256 + 8 * sub);
        layer_tab<16>(y, tf4 + 4 * 256 + 8 * sub);
    } else {
        layer_notab<1 ,false,0>(y, ang + 0 * NANG, sub);
        layer_notab<2 ,false,1>(y, ang + 1 * NANG, sub);
        layer_notab<4 ,false,2>(y, ang + 2 * NANG, sub);
        layer_notab<8 ,false,3>(y, ang + 3 * NANG, sub);
        layer_notab<16,false,4>(y, ang + 4 * NANG, sub);
    }
    #pragma unroll
    for (int u = 0; u < 16; ++u)
        *reinterpret_cast<float4*>(&base[((sub << 5) + 2 * u) ^ xr]) =
            make_float4(y[2*u].x, y[2*u].y, y[2*u+1].x, y[2*u+1].y);
    __syncthreads();
    #pragma unroll
    for (int i = 0; i < 32; ++i) y[i] = base[rowB(sub, i) ^ xr];

    if (USE_TAB) {
        layer_tab<1 >(y, tf4 + 5 * 256 + 8 * sub);
        layer_tab<2 >(y, tf4 + 6 * 256 + 8 * sub);
        layer_tab<4 >(y, tf4 + 7 * 256 + 8 * sub);
        layer_tab<8 >(y, tf4 + 8 * 256 + 8 * sub);
        layer_tab<16>(y, tf4 + 9 * 256 + 8 * sub);
    } else {
        layer_notab<1 ,true,5>(y, ang + 5 * NANG, sub);
        layer_notab<2 ,true,6>(y, ang + 6 * NANG, sub);
        layer_notab<4 ,true,7>(y, ang + 7 * NANG, sub);
        layer_notab<8 ,true,8>(y, ang + 8 * NANG, sub);
        layer_notab<16,true,9>(y, ang + 9 * NANG, sub);
    }
    __syncthreads();
    #pragma unroll
    for (int i = 0; i < 32; ++i) base[rowB(sub, i) ^ xr] = y[i];
    __syncthreads();
    #pragma unroll
    for (int u = 0; u < 16; ++u) {
        float4 v = *reinterpret_cast<const float4*>(&base[((sub << 5) + 2 * u) ^ xr]);
        y[2*u].x = v.x; y[2*u].y = v.y; y[2*u+1].x = v.z; y[2*u+1].y = v.w;
    }

    if (USE_TAB) {
        layer_tab<1 >(y, tf4 + 10 * 256 + 8 * sub);
        layer_tab<2 >(y, tf4 + 11 * 256 + 8 * sub);
        layer_tab<4 >(y, tf4 + 12 * 256 + 8 * sub);
        layer_tab<8 >(y, tf4 + 13 * 256 + 8 * sub);
        layer_tab<16>(y, tf4 + 14 * 256 + 8 * sub);
    } else {
        layer_notab<1 ,false,0>(y, ang + 10 * NANG, sub);
        layer_notab<2 ,false,1>(y, ang + 11 * NANG, sub);
        layer_notab<4 ,false,2>(y, ang + 12 * NANG, sub);
        layer_notab<8 ,false,3>(y, ang + 13 * NANG, sub);
        layer_notab<16,false,4>(y, ang + 14 * NANG, sub);
    }
    __syncthreads();
    #pragma unroll
    for (int u = 0; u < 16; ++u)
        *reinterpret_cast<float4*>(&base[((sub << 5) + 2 * u) ^ xr]) =
            make_float4(y[2*u].x, y[2*u].y, y[2*u+1].x, y[2*u+1].y);
    __syncthreads();
    #pragma unroll
    for (int i = 0; i < 32; ++i) y[i] = base[rowB(sub, i) ^ xr];

    if (USE_TAB) {
        layer_tab<1 >(y, tf4 + 15 * 256 + 8 * sub);
        layer_tab<2 >(y, tf4 + 16 * 256 + 8 * sub);
        layer_tab<4 >(y, tf4 + 17 * 256 + 8 * sub);
        layer_tab<8 >(y, tf4 + 18 * 256 + 8 * sub);
        layer_tab<16>(y, tf4 + 19 * 256 + 8 * sub);
    } else {
        layer_notab<1 ,true,5>(y, ang + 15 * NANG, sub);
        layer_notab<2 ,true,6>(y, ang + 16 * NANG, sub);
        layer_notab<4 ,true,7>(y, ang + 17 * NANG, sub);
        layer_notab<8 ,true,8>(y, ang + 18 * NANG, sub);
        layer_notab<16,true,9>(y, ang + 19 * NANG, sub);
    }

    v2f* Op = reinterpret_cast<v2f*>(out) + col2;
    #pragma unroll
    for (int i = 0; i < 32; ++i)
        Op[rowB(sub, i) * BATCH2] = y[i];
}

extern "C" void kernel_launch(void* const* d_in, const int* in_sizes, int n_in,
                              void* d_out, int out_size, void* d_ws, size_t ws_size,
                              hipStream_t stream) {
    (void)in_sizes; (void)n_in; (void)out_size;
    const float* X   = (const float*)d_in[0];
    const float* ang = (const float*)d_in[1];
    float* out = (float*)d_out;

    if (d_ws != nullptr && ws_size >= WS_MFMA_BYTES) {
        unsigned short* whi = (unsigned short*)d_ws;
        unsigned short* wlo = whi + 4 * 32 * 1024;
        build_w_kernel<<<64, 64, 0, stream>>>(ang, whi, wlo);
        mfma_kernel<<<512, 512, 0, stream>>>(X, whi, out);
    } else if (d_ws != nullptr && ws_size >= TAB_BYTES) {
        float2* tab = (float2*)d_ws;
        build_tab_kernel<<<(TAB_ELEMS + 255) / 256, 256, 0, stream>>>(ang, tab);
        butterfly_kernel<true><<<512, 256, 0, stream>>>(X, ang, tab, out);
    } else {
        butterfly_kernel<false><<<512, 256, 0, stream>>>(X, ang, nullptr, out);
    }
}